// Round 8
// baseline (1525.002 us; speedup 1.0000x reference)
//
#include <hip/hip_runtime.h>
#include <hip/hip_bf16.h>

// FastBinaryLinear: y[t,o] = scale[o] * sum_i x[t,i]*sign(w[o,i])
// R8: i8 path, 256x256 tile with BK=64 i8 -> LDS 64 KiB -> 2 blocks/CU
// (4 waves/SIMD). Cross-block TLP hides staging/barrier stalls (m114).
// Schedule per iter (2 K-tiles): 4 phases [stage; VMC; reads; BAR; MFMA; BAR].

typedef int i32x4 __attribute__((ext_vector_type(4)));
typedef const __attribute__((address_space(1))) void* gptr_t;
typedef __attribute__((address_space(3))) void* lptr_t;

template<bool V> struct BoolC { static constexpr bool value = V; };

// ---- fused pre-pass: blocks [0,M) quantize x rows; [M, M+N) sign w rows ----
__global__ __launch_bounds__(256) void prep_kernel(
    const float4* __restrict__ x, const float4* __restrict__ w,
    unsigned* __restrict__ xq, unsigned* __restrict__ wq,
    float* __restrict__ alpha, int M, int N, int K) {
  const int bid = blockIdx.x;
  const int t = threadIdx.x;
  const int n4 = K >> 2;

  if (bid < M) {
    const int row = bid;
    const float4* xr = x + (size_t)row * n4;
    unsigned* qr = xq + (size_t)row * n4;

    float m = 0.f;
    for (int i = t; i < n4; i += 256) {
      float4 v = xr[i];
      m = fmaxf(m, fmaxf(fmaxf(fabsf(v.x), fabsf(v.y)), fmaxf(fabsf(v.z), fabsf(v.w))));
    }
    for (int o = 32; o > 0; o >>= 1) m = fmaxf(m, __shfl_xor(m, o));
    __shared__ float wm[4];
    if ((t & 63) == 0) wm[t >> 6] = m;
    __syncthreads();
    m = fmaxf(fmaxf(wm[0], wm[1]), fmaxf(wm[2], wm[3]));

    const float inv = m > 0.f ? 127.f / m : 0.f;
    if (t == 0) alpha[row] = m > 0.f ? m / 127.f : 0.f;

    for (int i = t; i < n4; i += 256) {
      float4 v = xr[i];  // L1/L2-resident re-read
      int q0 = (int)rintf(v.x * inv), q1 = (int)rintf(v.y * inv);
      int q2 = (int)rintf(v.z * inv), q3 = (int)rintf(v.w * inv);
      qr[i] = (unsigned)(q0 & 255) | ((unsigned)(q1 & 255) << 8) |
              ((unsigned)(q2 & 255) << 16) | ((unsigned)(q3 & 255) << 24);
    }
  } else {
    const int row = bid - M;
    const float4* wr = w + (size_t)row * n4;
    unsigned* qr = wq + (size_t)row * n4;
    for (int i = t; i < n4; i += 256) {
      float4 f = wr[i];
      int s0 = (f.x > 0.f) - (f.x < 0.f);
      int s1 = (f.y > 0.f) - (f.y < 0.f);
      int s2 = (f.z > 0.f) - (f.z < 0.f);
      int s3 = (f.w > 0.f) - (f.w < 0.f);
      qr[i] = (unsigned)(s0 & 255) | ((unsigned)(s1 & 255) << 8) |
              ((unsigned)(s2 & 255) << 16) | ((unsigned)(s3 & 255) << 24);
    }
  }
}

// ---- 256x256 BK=64 i8 GEMM: C = A[M][K]i8 * B[N][K]^T i8, i32 exact ----
// Per-buffer LDS (32 KB): A = 16 subtiles(16r x 64B) @0, B same @16384.
// Stored granule slot s = g ^ ((row>>1)&3); staging thread t fetches
// chunk (t&3)^((t>>3)&3) of row t>>2; reader lane (rho,G) reads slot
// G^((rho>>1)&3). 2 lanes/16B-slot per quarter-wave -> conflict-free.
__global__ __launch_bounds__(512, 4) void gemm256_i8_kernel(
    const signed char* __restrict__ A,   // [M][K] i8 (quantized x)
    const signed char* __restrict__ B,   // [N][K] i8 (sign w)
    const float* __restrict__ scale,     // [N]
    const float* __restrict__ alpha,     // [M]
    float* __restrict__ C,               // [M][N] f32
    int M, int N, int K) {
  __shared__ __align__(16) char lds[65536];

  const int t = threadIdx.x;
  const int lane = t & 63;
  const int wv = t >> 6;
  const int wm = wv >> 2;   // 0..1
  const int wn = wv & 3;    // 0..3

  const int nbn = N >> 8;
  const int bn = blockIdx.x % nbn;
  const int bm = blockIdx.x / nbn;
  const int m0 = bm << 8, n0 = bn << 8;

  // staging coords: 8KB issue = 128 rows x 64 B; thread t -> row t>>2,
  // slot t&3, fetching inverse-swizzled global chunk gsw.
  const int rlo = t >> 2;                      // 0..127
  const int gsw = (t & 3) ^ ((t >> 3) & 3);    // data chunk for this slot
  const signed char* gA = A + (size_t)(m0 + rlo) * K + gsw * 16;
  const signed char* gB = B + (size_t)(n0 + rlo) * K + gsw * 16;
  const int stBase = wv << 10;  // wave-uniform LDS base; HW adds lane*16

  // ds_read lane bases
  const int rho = lane & 15;
  const int gix = (lane >> 4) ^ ((rho >> 1) & 3);
  const int dsA = (wm << 13) + (rho << 6) + (gix << 4);           // wm*8KB
  const int dsB = 16384 + (wn << 12) + (rho << 6) + (gix << 4);   // wn*4KB

#define STAGE_A(H, KT, BUF)                                                   \
  __builtin_amdgcn_global_load_lds(                                           \
      (gptr_t)(gA + (size_t)((H)*128) * K + (size_t)(KT)*64),                 \
      (lptr_t)(lds + (BUF)*32768 + (H)*8192 + stBase), 16, 0, 0)
#define STAGE_B(H, KT, BUF)                                                   \
  __builtin_amdgcn_global_load_lds(                                           \
      (gptr_t)(gB + (size_t)((H)*128) * K + (size_t)(KT)*64),                 \
      (lptr_t)(lds + (BUF)*32768 + 16384 + (H)*8192 + stBase), 16, 0, 0)
#define STAGE_T(KT, BUF) \
  STAGE_A(0, KT, BUF); STAGE_A(1, KT, BUF); STAGE_B(0, KT, BUF); STAGE_B(1, KT, BUF)

#define RD_A(MF, BUF) (*(const i32x4*)(lds + (BUF)*32768 + dsA + (MF)*1024))
#define RD_B(NF, BUF) (*(const i32x4*)(lds + (BUF)*32768 + dsB + (NF)*1024))
#define BAR() asm volatile("s_barrier" ::: "memory")
#define VMC(N) asm volatile("s_waitcnt vmcnt(" #N ")" ::: "memory")
#define LOAD_A4(MF0, BUF)                                             \
  _Pragma("unroll")                                                   \
  for (int j = 0; j < 4; j++) aq[j] = RD_A((MF0) + j, BUF)
#define LOAD_B4(BUF)                                                  \
  _Pragma("unroll")                                                   \
  for (int nf = 0; nf < 4; nf++) bq[nf] = RD_B(nf, BUF)
#define MFMA16(MF0)                                                   \
  __builtin_amdgcn_s_setprio(1);                                      \
  _Pragma("unroll")                                                   \
  for (int j = 0; j < 4; j++)                                         \
    _Pragma("unroll")                                                 \
    for (int nf = 0; nf < 4; nf++)                                    \
      acc[(MF0) + j][nf] = __builtin_amdgcn_mfma_i32_16x16x64_i8(     \
          aq[j], bq[nf], acc[(MF0) + j][nf], 0, 0, 0);                \
  __builtin_amdgcn_s_setprio(0)

  i32x4 acc[8][4];
#pragma unroll
  for (int i = 0; i < 8; i++)
#pragma unroll
    for (int j = 0; j < 4; j++) acc[i][j] = (i32x4)(0);

  i32x4 aq[4], bq[4];

  // ---- prologue: T0 -> b0, T1 -> b1 (8 issues); wait T0 ----
  STAGE_T(0, 0);
  STAGE_T(1, 1);
  VMC(4);
  BAR();

  // Per iter (b0 = T_{2i}, b1 = T_{2i+1}):
  //  P0: [!FIRST: stage b1<-T_{2i+1}] VMC(4)->b0 ready; B+A-hi reads; MFMA hi
  //  P1: A-lo reads; MFMA lo                       [b0 fully read]
  //  P2: [FULL: stage b0<-T_{2i+2}; VMC(4)] else VMC(0) ->b1 ready; reads; MFMA hi
  //  P3: A-lo reads; MFMA lo                       [b1 fully read]
  auto run_iter = [&](int i, auto firstc, auto fullc) {
    constexpr bool FIRST = decltype(firstc)::value;
    constexpr bool FULL = decltype(fullc)::value;
    const int kt1 = 2 * i + 1, kt2 = 2 * i + 2;

    // ===== P0 =====
    if constexpr (!FIRST) { STAGE_T(kt1, 1); }
    VMC(4);
    LOAD_B4(0);
    LOAD_A4(4, 0);
    BAR();
    MFMA16(4);
    BAR();

    // ===== P1 =====
    LOAD_A4(0, 0);
    BAR();
    MFMA16(0);
    BAR();

    // ===== P2 =====
    if constexpr (FULL) { STAGE_T(kt2, 0); VMC(4); }
    else                { VMC(0); }
    LOAD_B4(1);
    LOAD_A4(4, 1);
    BAR();
    MFMA16(4);
    BAR();

    // ===== P3 =====
    LOAD_A4(0, 1);
    BAR();
    MFMA16(0);
    BAR();
  };

  const int nt = K >> 7;   // 128 i8 per iter (2 tiles x 64)
  if (nt == 1) {
    run_iter(0, BoolC<true>{}, BoolC<false>{});
  } else {
    run_iter(0, BoolC<true>{}, BoolC<true>{});
    for (int i = 1; i < nt - 1; ++i) run_iter(i, BoolC<false>{}, BoolC<true>{});
    run_iter(nt - 1, BoolC<false>{}, BoolC<false>{});
  }

  // ---- epilogue: C/D col=lane&15, row=(lane>>4)*4+j; y = acc*alpha*scale ----
  const int cc = lane & 15;
  const int cr4 = (lane >> 4) << 2;
#pragma unroll
  for (int nf = 0; nf < 4; nf++) {
    const int col = n0 + wn * 64 + nf * 16 + cc;
    const float s = scale[col];
#pragma unroll
    for (int mf = 0; mf < 8; mf++) {
      const int row = m0 + wm * 128 + mf * 16 + cr4;
#pragma unroll
      for (int j = 0; j < 4; j++)
        C[(size_t)(row + j) * N + col] = (float)acc[mf][nf][j] * (s * alpha[row + j]);
    }
  }
#undef STAGE_A
#undef STAGE_B
#undef STAGE_T
#undef RD_A
#undef RD_B
#undef BAR
#undef VMC
#undef LOAD_A4
#undef LOAD_B4
#undef MFMA16
}

// ---- fallback: f32 tiled GEMM (odd shapes / tiny ws) ----
__global__ __launch_bounds__(256) void fallback_gemm_kernel(
    const float* __restrict__ x, const float* __restrict__ w,
    const float* __restrict__ scale, float* __restrict__ out,
    int M, int N, int K) {
  __shared__ float xs[16][17];
  __shared__ float ws_[16][17];
  int nb = N / 16;
  int bx = blockIdx.x % nb;
  int by = blockIdx.x / nb;
  int tx = threadIdx.x % 16;
  int ty = threadIdx.x / 16;
  float acc = 0.f;
  for (int k0 = 0; k0 < K; k0 += 16) {
    xs[ty][tx] = x[(size_t)(by * 16 + ty) * K + k0 + tx];
    float wv = w[(size_t)(bx * 16 + ty) * K + k0 + tx];
    ws_[ty][tx] = (float)((wv > 0.f) - (wv < 0.f));
    __syncthreads();
#pragma unroll
    for (int kk = 0; kk < 16; kk++) acc += xs[ty][kk] * ws_[tx][kk];
    __syncthreads();
  }
  int row = by * 16 + ty, col = bx * 16 + tx;
  out[(size_t)row * N + col] = acc * scale[col];
}

extern "C" void kernel_launch(void* const* d_in, const int* in_sizes, int n_in,
                              void* d_out, int out_size, void* d_ws, size_t ws_size,
                              hipStream_t stream) {
  const float* x = (const float*)d_in[0];
  const float* w = (const float*)d_in[1];
  const float* scale = (const float*)d_in[2];
  float* out = (float*)d_out;

  const int N = in_sizes[2];
  const int K = in_sizes[1] / N;
  const int M = in_sizes[0] / K;

  const size_t xq_bytes = (size_t)M * K;
  const size_t wq_bytes = (size_t)N * K;
  const size_t al_bytes = (size_t)M * 4;
  const bool shapes_ok = (M % 256 == 0) && (N % 256 == 0) && (K % 1024 == 0);

  if (shapes_ok && ws_size >= xq_bytes + wq_bytes + al_bytes) {
    signed char* xq = (signed char*)d_ws;
    signed char* wq = (signed char*)((char*)d_ws + xq_bytes);
    float* alpha = (float*)((char*)d_ws + xq_bytes + wq_bytes);

    prep_kernel<<<M + N, 256, 0, stream>>>((const float4*)x, (const float4*)w,
                                           (unsigned*)xq, (unsigned*)wq, alpha, M, N, K);

    int grid = (M / 256) * (N / 256);
    gemm256_i8_kernel<<<grid, 512, 0, stream>>>(xq, wq, scale, alpha, out, M, N, K);
  } else {
    int grid = (M / 16) * (N / 16);
    fallback_gemm_kernel<<<grid, 256, 0, stream>>>(x, w, scale, out, M, N, K);
  }
}

// Round 10
// 194.484 us; speedup vs baseline: 7.8413x; 7.8413x over previous
//
#include <hip/hip_runtime.h>
#include <hip/hip_bf16.h>

// FastBinaryLinear: y[t,o] = scale[o] * sum_i x[t,i]*sign(w[o,i])
// R10: i8 path, 128x256 tile, BK=64, 8 waves (64x64/wave, acc=64 VGPR),
// TRIPLE-buffered LDS (3 x 24KB = 72KB) -> 2 blocks/CU. Gate discipline
// fixed (r9 race): every VMC at phase END before BAR (per-wave vmcnt +
// barrier => all waves' staging slices complete before any wave reads).

typedef int i32x4 __attribute__((ext_vector_type(4)));
typedef const __attribute__((address_space(1))) void* gptr_t;
typedef __attribute__((address_space(3))) void* lptr_t;

template<bool V> struct BoolC { static constexpr bool value = V; };

// ---- fused pre-pass: blocks [0,M) quantize x rows; [M, M+N) sign w rows ----
__global__ __launch_bounds__(256) void prep_kernel(
    const float4* __restrict__ x, const float4* __restrict__ w,
    unsigned* __restrict__ xq, unsigned* __restrict__ wq,
    float* __restrict__ alpha, int M, int N, int K) {
  const int bid = blockIdx.x;
  const int t = threadIdx.x;
  const int n4 = K >> 2;

  if (bid < M) {
    const int row = bid;
    const float4* xr = x + (size_t)row * n4;
    unsigned* qr = xq + (size_t)row * n4;

    float m = 0.f;
    for (int i = t; i < n4; i += 256) {
      float4 v = xr[i];
      m = fmaxf(m, fmaxf(fmaxf(fabsf(v.x), fabsf(v.y)), fmaxf(fabsf(v.z), fabsf(v.w))));
    }
    for (int o = 32; o > 0; o >>= 1) m = fmaxf(m, __shfl_xor(m, o));
    __shared__ float wm_[4];
    if ((t & 63) == 0) wm_[t >> 6] = m;
    __syncthreads();
    m = fmaxf(fmaxf(wm_[0], wm_[1]), fmaxf(wm_[2], wm_[3]));

    const float inv = m > 0.f ? 127.f / m : 0.f;
    if (t == 0) alpha[row] = m > 0.f ? m / 127.f : 0.f;

    for (int i = t; i < n4; i += 256) {
      float4 v = xr[i];  // cache-resident re-read
      int q0 = (int)rintf(v.x * inv), q1 = (int)rintf(v.y * inv);
      int q2 = (int)rintf(v.z * inv), q3 = (int)rintf(v.w * inv);
      qr[i] = (unsigned)(q0 & 255) | ((unsigned)(q1 & 255) << 8) |
              ((unsigned)(q2 & 255) << 16) | ((unsigned)(q3 & 255) << 24);
    }
  } else {
    const int row = bid - M;
    const float4* wr = w + (size_t)row * n4;
    unsigned* qr = wq + (size_t)row * n4;
    for (int i = t; i < n4; i += 256) {
      float4 f = wr[i];
      int s0 = (f.x > 0.f) - (f.x < 0.f);
      int s1 = (f.y > 0.f) - (f.y < 0.f);
      int s2 = (f.z > 0.f) - (f.z < 0.f);
      int s3 = (f.w > 0.f) - (f.w < 0.f);
      qr[i] = (unsigned)(s0 & 255) | ((unsigned)(s1 & 255) << 8) |
              ((unsigned)(s2 & 255) << 16) | ((unsigned)(s3 & 255) << 24);
    }
  }
}

// ---- 128x256 BK=64 i8 GEMM, triple-buffered ----
// Per-buffer LDS (24 KB): A = 8 subtiles(16r x 64B) @0, B = 16 subtiles
// @8192. Slot swizzle (r8/r9-verified geometry): stored slot s holds
// global chunk s ^ ((row>>1)&3); reader lane (rho,G) reads slot
// G ^ ((rho>>1)&3).
__global__ __launch_bounds__(512, 4) void gemm128_i8_kernel(
    const signed char* __restrict__ A,   // [M][K] i8 (quantized x)
    const signed char* __restrict__ B,   // [N][K] i8 (sign w)
    const float* __restrict__ scale,     // [N]
    const float* __restrict__ alpha,     // [M]
    float* __restrict__ C,               // [M][N] f32
    int M, int N, int K) {
  __shared__ __align__(16) char lds[73728];   // 3 x 24576

  const int t = threadIdx.x;
  const int lane = t & 63;
  const int wv = t >> 6;
  const int wm = wv >> 2;   // 0..1 (64-row half of BM=128)
  const int wn = wv & 3;    // 0..3 (64-col quarter of BN=256)

  const int nbn = N >> 8;
  const int bn = blockIdx.x % nbn;
  const int bm = blockIdx.x / nbn;
  const int m0 = bm << 7, n0 = bn << 8;

  // staging: 8KB issue = 128 rows x 64 B; thread t -> row t>>2, slot t&3
  const int rlo = t >> 2;                      // 0..127
  const int gsw = (t & 3) ^ ((t >> 3) & 3);    // inverse-swizzled chunk
  const signed char* gA = A + (size_t)(m0 + rlo) * K + gsw * 16;
  const signed char* gB = B + (size_t)(n0 + rlo) * K + gsw * 16;
  const int stBase = wv << 10;  // wave-uniform; HW adds lane*16

  // ds_read lane bases
  const int rho = lane & 15;
  const int gix = (lane >> 4) ^ ((rho >> 1) & 3);
  const int dsA = (wm << 12) + (rho << 6) + (gix << 4);          // A@0
  const int dsB = 8192 + (wn << 12) + (rho << 6) + (gix << 4);   // B@8K

#define STAGE_A(KT, OFF)                                                      \
  __builtin_amdgcn_global_load_lds(                                           \
      (gptr_t)(gA + (size_t)(KT)*64),                                         \
      (lptr_t)(lds + (OFF) + stBase), 16, 0, 0)
#define STAGE_B(H, KT, OFF)                                                   \
  __builtin_amdgcn_global_load_lds(                                           \
      (gptr_t)(gB + (size_t)((H)*128) * K + (size_t)(KT)*64),                 \
      (lptr_t)(lds + (OFF) + 8192 + (H)*8192 + stBase), 16, 0, 0)
#define STAGE_T(KT, OFF) STAGE_A(KT, OFF); STAGE_B(0, KT, OFF); STAGE_B(1, KT, OFF)

#define RD_A(MF, OFF) (*(const i32x4*)(lds + (OFF) + dsA + (MF)*1024))
#define RD_B(NF, OFF) (*(const i32x4*)(lds + (OFF) + dsB + (NF)*1024))
#define BAR() asm volatile("s_barrier" ::: "memory")
#define VMC(N) asm volatile("s_waitcnt vmcnt(" #N ")" ::: "memory")
#define LOAD_A2(MF0, OFF)                                             \
  aq[0] = RD_A(MF0, OFF); aq[1] = RD_A((MF0) + 1, OFF)
#define LOAD_B4(OFF)                                                  \
  _Pragma("unroll")                                                   \
  for (int nf = 0; nf < 4; nf++) bq[nf] = RD_B(nf, OFF)
#define MFMA8(MF0)                                                    \
  __builtin_amdgcn_s_setprio(1);                                      \
  _Pragma("unroll")                                                   \
  for (int j = 0; j < 2; j++)                                         \
    _Pragma("unroll")                                                 \
    for (int nf = 0; nf < 4; nf++)                                    \
      acc[(MF0) + j][nf] = __builtin_amdgcn_mfma_i32_16x16x64_i8(     \
          aq[j], bq[nf], acc[(MF0) + j][nf], 0, 0, 0);                \
  __builtin_amdgcn_s_setprio(0)

  i32x4 acc[4][4];
#pragma unroll
  for (int i = 0; i < 4; i++)
#pragma unroll
    for (int j = 0; j < 4; j++) acc[i][j] = (i32x4)(0);

  i32x4 aq[2], bq[4];

  // ---- prologue: T0->buf0, T1->buf1; drain T0 (all waves), barrier ----
  STAGE_T(0, 0);
  STAGE_T(1, 24576);
  VMC(3);
  BAR();

  // Tile j reads buf rd = 24576*(j%3); stages T_{j+2} into st = buf just
  // vacated by T_{j-1}.  Gates at PHASE END before BAR (r5 discipline):
  //   tile-j phase B end: VMC(3) -> T_{j+1} complete (T_{j+2} stays in
  //   flight); penultimate tile: VMC(0); last tile: none.
  auto tile = [&](int kt, int rd, int st, auto stagec, auto gzc) {
    constexpr bool STG = decltype(stagec)::value;  // stage kt+2 & VMC(3)
    constexpr bool GZ = decltype(gzc)::value;      // penultimate: VMC(0)
    // ===== phase A: B4 + A-hi, MFMA hi =====
    LOAD_B4(rd);
    LOAD_A2(2, rd);
    BAR();
    MFMA8(2);
    BAR();
    // ===== phase B: A-lo, stage, MFMA lo, gate =====
    LOAD_A2(0, rd);
    if constexpr (STG) { STAGE_T(kt + 2, st); }
    BAR();
    MFMA8(0);
    if constexpr (STG) { VMC(3); }
    else if constexpr (GZ) { VMC(0); }
    BAR();
  };

  const int nt2 = K >> 6;   // #64-byte K-tiles (>= 4 by shape guard)
  int rd = 0;
  for (int j = 0; j < nt2 - 2; ++j) {
    const int st = (rd + 49152 >= 73728) ? rd - 24576 : rd + 49152;
    tile(j, rd, st, BoolC<true>{}, BoolC<false>{});
    rd = (rd == 49152) ? 0 : rd + 24576;
  }
  tile(nt2 - 2, rd, 0, BoolC<false>{}, BoolC<true>{});
  rd = (rd == 49152) ? 0 : rd + 24576;
  tile(nt2 - 1, rd, 0, BoolC<false>{}, BoolC<false>{});

  // ---- epilogue: C/D col=lane&15, row=(lane>>4)*4+j; y = acc*alpha*scale ----
  const int cc = lane & 15;
  const int cr4 = (lane >> 4) << 2;
#pragma unroll
  for (int nf = 0; nf < 4; nf++) {
    const int col = n0 + wn * 64 + nf * 16 + cc;
    const float s = scale[col];
#pragma unroll
    for (int mf = 0; mf < 4; mf++) {
      const int row = m0 + wm * 64 + mf * 16 + cr4;
#pragma unroll
      for (int j = 0; j < 4; j++)
        C[(size_t)(row + j) * N + col] = (float)acc[mf][nf][j] * (s * alpha[row + j]);
    }
  }
#undef STAGE_A
#undef STAGE_B
#undef STAGE_T
#undef RD_A
#undef RD_B
#undef BAR
#undef VMC
#undef LOAD_A2
#undef LOAD_B4
#undef MFMA8
}

// ---- fallback: f32 tiled GEMM (odd shapes / tiny ws) ----
__global__ __launch_bounds__(256) void fallback_gemm_kernel(
    const float* __restrict__ x, const float* __restrict__ w,
    const float* __restrict__ scale, float* __restrict__ out,
    int M, int N, int K) {
  __shared__ float xs[16][17];
  __shared__ float ws_[16][17];
  int nb = N / 16;
  int bx = blockIdx.x % nb;
  int by = blockIdx.x / nb;
  int tx = threadIdx.x % 16;
  int ty = threadIdx.x / 16;
  float acc = 0.f;
  for (int k0 = 0; k0 < K; k0 += 16) {
    xs[ty][tx] = x[(size_t)(by * 16 + ty) * K + k0 + tx];
    float wv = w[(size_t)(bx * 16 + ty) * K + k0 + tx];
    ws_[ty][tx] = (float)((wv > 0.f) - (wv < 0.f));
    __syncthreads();
#pragma unroll
    for (int kk = 0; kk < 16; kk++) acc += xs[ty][kk] * ws_[tx][kk];
    __syncthreads();
  }
  int row = by * 16 + ty, col = bx * 16 + tx;
  out[(size_t)row * N + col] = acc * scale[col];
}

extern "C" void kernel_launch(void* const* d_in, const int* in_sizes, int n_in,
                              void* d_out, int out_size, void* d_ws, size_t ws_size,
                              hipStream_t stream) {
  const float* x = (const float*)d_in[0];
  const float* w = (const float*)d_in[1];
  const float* scale = (const float*)d_in[2];
  float* out = (float*)d_out;

  const int N = in_sizes[2];
  const int K = in_sizes[1] / N;
  const int M = in_sizes[0] / K;

  const size_t xq_bytes = (size_t)M * K;
  const size_t wq_bytes = (size_t)N * K;
  const size_t al_bytes = (size_t)M * 4;
  const bool shapes_ok = (M % 128 == 0) && (N % 256 == 0) && (K % 128 == 0) && (K >= 256);

  if (shapes_ok && ws_size >= xq_bytes + wq_bytes + al_bytes) {
    signed char* xq = (signed char*)d_ws;
    signed char* wq = (signed char*)((char*)d_ws + xq_bytes);
    float* alpha = (float*)((char*)d_ws + xq_bytes + wq_bytes);

    prep_kernel<<<M + N, 256, 0, stream>>>((const float4*)x, (const float4*)w,
                                           (unsigned*)xq, (unsigned*)wq, alpha, M, N, K);

    int grid = (M / 128) * (N / 256);
    gemm128_i8_kernel<<<grid, 512, 0, stream>>>(xq, wq, scale, alpha, out, M, N, K);
  } else {
    int grid = (M / 16) * (N / 16);
    fallback_gemm_kernel<<<grid, 256, 0, stream>>>(x, w, scale, out, M, N, K);
  }
}